// Round 8
// baseline (3238.373 us; speedup 1.0000x reference)
//
#include <hip/hip_runtime.h>
#include <hip/hip_fp16.h>

// Problem: B=256, T=512, F=64, H=128  (GRU-D / BRITS-style recurrence)
// d_out (fp32): [0]=loss, [1..256]=predictions, [257..]=imputations [B,T,F]

#define NBATCH 256
#define NT 512
#define NF 64
#define NH 128
#define BPB 16                 // batch elements per block (MFMA M dimension)

// ---- workspace byte offsets ----
#define WHH_OFF   0u           // [16][512] uint4 packed f16 rows of W_hh
#define WIH_OFF   131072u      // [16][512] uint4 packed f16 rows of W_ih
#define WHR_OFF   262144u      // [16][64]  uint4 packed f16 rows of W_hr
#define WFR_OFF   278528u      // [8][64]   uint4 packed f16 rows of W_fr (diag zeroed)
#define INVMS_OFF 286720u      // f32[512]
#define ISTR_OFF  288768u      // f32[1]
#define GH_OFF    294912u      // f16 [B*T*128] gamma_h
#define AL_OFF    33849344u    // f16 [B*T*64]  alpha

typedef _Float16 f16x8 __attribute__((ext_vector_type(8)));
typedef float f32x4 __attribute__((ext_vector_type(4)));
typedef _Float16 half2_t __attribute__((ext_vector_type(2)));

__device__ __forceinline__ unsigned pack2(float a, float b) {
    __half2 h = __floats2half2_rn(a, b);
    return __builtin_bit_cast(unsigned, h);
}

__device__ __forceinline__ float dot2f(unsigned w, unsigned a, float acc) {
#if __has_builtin(__builtin_amdgcn_fdot2)
    return __builtin_amdgcn_fdot2(__builtin_bit_cast(half2_t, w),
                                  __builtin_bit_cast(half2_t, a), acc, false);
#else
    float2 wf = __half22float2(__builtin_bit_cast(__half2, w));
    float2 af = __half22float2(__builtin_bit_cast(__half2, a));
    return acc + wf.x * af.x + wf.y * af.y;
#endif
}

__device__ __forceinline__ float sigm(float x) { return 1.f / (1.f + __expf(-x)); }
__device__ __forceinline__ float tanh_fast(float x) { return 1.f - 2.f / (__expf(2.f * x) + 1.f); }

__device__ __forceinline__ f16x8 as_h8(uint4 u) { return __builtin_bit_cast(f16x8, u); }

// A-fragment (M=16,K=32) from LDS row-major [row][K...]: lane l supplies
// row=l&15, k=(l>>4)*8+e. A and B use the SAME k-gather so any internal
// k-permutation cancels in the contraction. (Verified: R7 passed absmax.)
__device__ __forceinline__ f16x8 ldA(const __half* row, int lg, int q) {
    return as_h8(*(const uint4*)(row + q * 32 + lg * 8));
}

// LDS-only barrier: global loads/stores stay in flight (loads wait at their
// register-use site; stores drain at s_endpgm). All cross-wave traffic in
// main_kernel is LDS, which lgkmcnt(0) fully orders.
__device__ __forceinline__ void bar_lds() {
    asm volatile("s_waitcnt lgkmcnt(0)\n\ts_barrier" ::: "memory");
}

// ---------------------------------------------------------------------------
// prep_w: pack W_hh / W_ih / W_hr / W_fr(zero-diag) rows into f16x2 uint4 layout
// ---------------------------------------------------------------------------
__global__ __launch_bounds__(256) void prep_w(const float* __restrict__ Whh,
                                              const float* __restrict__ Wih,
                                              const float* __restrict__ Whr,
                                              const float* __restrict__ Wfr,
                                              unsigned* __restrict__ wsu) {
    int o = blockIdx.x * 256 + threadIdx.x;
    float v0, v1;
    if (o < 32768) {                      // W_hh [512][128]
        int c = o & 3, r = (o >> 2) & 511, cb = o >> 11;
        int col = 8 * cb + 2 * c;
        v0 = Whh[r * 128 + col]; v1 = Whh[r * 128 + col + 1];
    } else if (o < 65536) {               // W_ih [512][128]
        int o2 = o - 32768;
        int c = o2 & 3, r = (o2 >> 2) & 511, cb = o2 >> 11;
        int col = 8 * cb + 2 * c;
        v0 = Wih[r * 128 + col]; v1 = Wih[r * 128 + col + 1];
    } else if (o < 69632) {               // W_hr [64][128]
        int o3 = o - 65536;
        int c = o3 & 3, f = (o3 >> 2) & 63, cb = o3 >> 8;
        int col = 8 * cb + 2 * c;
        v0 = Whr[f * 128 + col]; v1 = Whr[f * 128 + col + 1];
    } else if (o < 71680) {               // W_fr [64][64], zero diagonal
        int o4 = o - 69632;
        int c = o4 & 3, f = (o4 >> 2) & 63, cb = o4 >> 8;
        int col = 8 * cb + 2 * c;
        v0 = (col == f) ? 0.f : Wfr[f * 64 + col];
        v1 = (col + 1 == f) ? 0.f : Wfr[f * 64 + col + 1];
    } else {
        return;
    }
    wsu[o] = pack2(v0, v1);
}

// ---------------------------------------------------------------------------
// prep_msum
// ---------------------------------------------------------------------------
__global__ __launch_bounds__(256) void prep_msum(const float* __restrict__ masks,
                                                 const float* __restrict__ is_train,
                                                 float* __restrict__ invms,
                                                 float* __restrict__ inv_istr,
                                                 float* __restrict__ d_out0) {
    __shared__ float red[256];
    int tid = threadIdx.x;
    int t = blockIdx.x;
    if (t < NT) {
        int f = tid & 63, br = tid >> 6;
        float s = 0.f;
        for (int i = 0; i < 64; i++) {
            int b = br + i * 4;
            s += masks[((size_t)b * NT + t) * NF + f];
        }
        red[tid] = s;
        __syncthreads();
        for (int off = 128; off > 0; off >>= 1) {
            if (tid < off) red[tid] += red[tid + off];
            __syncthreads();
        }
        if (tid == 0) invms[t] = 1.f / (red[0] + 1e-5f);
    } else {
        red[tid] = is_train[tid];
        __syncthreads();
        for (int off = 128; off > 0; off >>= 1) {
            if (tid < off) red[tid] += red[tid + off];
            __syncthreads();
        }
        if (tid == 0) {
            *inv_istr = 1.f / (red[0] + 1e-5f);
            *d_out0 = 0.f;
        }
    }
}

// ---------------------------------------------------------------------------
// ga_kernel: precompute gamma_h[b,t,128] and alpha[b,t,64] (f16).
// ---------------------------------------------------------------------------
__global__ __launch_bounds__(256) void ga_kernel(const float* __restrict__ deltas,
                                                 const float* __restrict__ masks,
                                                 const float* __restrict__ Wdh,
                                                 const float* __restrict__ bdh,
                                                 const float* __restrict__ Wdx,
                                                 const float* __restrict__ bdx,
                                                 const float* __restrict__ Wwc,
                                                 const float* __restrict__ bwc,
                                                 __half* __restrict__ gh_all,
                                                 __half* __restrict__ al_all) {
    __shared__ unsigned wdhpk[32 * 128];
    __shared__ unsigned wwcpk[64 * 64];
    __shared__ float sbdh[128], sbdx[64], swdx[64], sbwc[64];
    __shared__ float dbuf[64];
    __shared__ __align__(16) unsigned dpk[32], gxpk[32], mpk2[32];
    int tid = threadIdx.x;

    for (int o = tid; o < 4096; o += 256) {
        int j = o & 127, k2 = o >> 7;
        wdhpk[o] = pack2(Wdh[j * 64 + 2 * k2], Wdh[j * 64 + 2 * k2 + 1]);
    }
    for (int o = tid; o < 4096; o += 256) {
        int f = o & 63, k2 = o >> 6;
        wwcpk[o] = pack2(Wwc[f * 128 + 2 * k2], Wwc[f * 128 + 2 * k2 + 1]);
    }
    if (tid < 128) sbdh[tid] = bdh[tid];
    if (tid < 64) {
        sbdx[tid] = bdx[tid];
        swdx[tid] = Wdx[tid * 65];
        sbwc[tid] = bwc[tid];
    }
    __syncthreads();

    for (int i = 0; i < 32; i++) {
        int p = blockIdx.x * 32 + i;
        if (tid < 32) {
            float2 dv = ((const float2*)(deltas + (size_t)p * NF))[tid];
            dbuf[2 * tid] = dv.x; dbuf[2 * tid + 1] = dv.y;
            dpk[tid] = pack2(dv.x, dv.y);
        } else if (tid < 64) {
            int q = tid - 32;
            float2 mv = ((const float2*)(masks + (size_t)p * NF))[q];
            mpk2[q] = pack2(mv.x, mv.y);
        }
        __syncthreads();
        if (tid < 64) {
            float gx = __expf(-fmaxf(dbuf[tid] * swdx[tid] + sbdx[tid], 0.f));
            float oth = __shfl_xor(gx, 1);
            if (!(tid & 1)) gxpk[tid >> 1] = pack2(gx, oth);
        }
        __syncthreads();
        if (tid < 128) {
            float a0 = sbdh[tid], a1 = 0.f;
            #pragma unroll
            for (int k8 = 0; k8 < 8; k8++) {
                uint4 dp = *(const uint4*)&dpk[4 * k8];
                a0 = dot2f(wdhpk[(4 * k8 + 0) * 128 + tid], dp.x, a0);
                a1 = dot2f(wdhpk[(4 * k8 + 1) * 128 + tid], dp.y, a1);
                a0 = dot2f(wdhpk[(4 * k8 + 2) * 128 + tid], dp.z, a0);
                a1 = dot2f(wdhpk[(4 * k8 + 3) * 128 + tid], dp.w, a1);
            }
            gh_all[(size_t)p * NH + tid] = __float2half(__expf(-fmaxf(a0 + a1, 0.f)));
        } else if (tid < 192) {
            int f = tid - 128;
            float a0 = sbwc[f], a1 = 0.f;
            #pragma unroll
            for (int k8 = 0; k8 < 8; k8++) {
                uint4 gp = *(const uint4*)&gxpk[4 * k8];
                a0 = dot2f(wwcpk[(4 * k8 + 0) * 64 + f], gp.x, a0);
                a1 = dot2f(wwcpk[(4 * k8 + 1) * 64 + f], gp.y, a1);
                a0 = dot2f(wwcpk[(4 * k8 + 2) * 64 + f], gp.z, a0);
                a1 = dot2f(wwcpk[(4 * k8 + 3) * 64 + f], gp.w, a1);
            }
            #pragma unroll
            for (int k8 = 0; k8 < 8; k8++) {
                uint4 mp = *(const uint4*)&mpk2[4 * k8];
                a0 = dot2f(wwcpk[(32 + 4 * k8 + 0) * 64 + f], mp.x, a0);
                a1 = dot2f(wwcpk[(32 + 4 * k8 + 1) * 64 + f], mp.y, a1);
                a0 = dot2f(wwcpk[(32 + 4 * k8 + 2) * 64 + f], mp.z, a0);
                a1 = dot2f(wwcpk[(32 + 4 * k8 + 3) * 64 + f], mp.w, a1);
            }
            al_all[(size_t)p * NF + f] = __float2half(a0 + a1);
        }
        __syncthreads();
    }
}

// ---------------------------------------------------------------------------
// main_kernel: 16 blocks, 512 threads, 16 batches/block. MFMA throughout.
// 2 lgkm-only barriers/step. Waves 0-3 redundantly compute x_h for ALL f so
// the x_c -> z_h transpose is wave-private (no barrier); each produces its
// own 16-f slice of c_c. Waves 4-7 stage inputs (2-step double-buffered,
// transposed) and do coalesced batched imp stores.
// ---------------------------------------------------------------------------
__global__ __launch_bounds__(512, 1) void main_kernel(
    const float* __restrict__ values, const float* __restrict__ masks,
    const float* __restrict__ labels, const float* __restrict__ is_train,
    const float* __restrict__ b_hr, const float* __restrict__ b_fr,
    const float* __restrict__ b_ih, const float* __restrict__ b_hh,
    const float* __restrict__ W_out, const float* __restrict__ b_out,
    const uint4* __restrict__ whh_ws, const uint4* __restrict__ wih_ws,
    const uint4* __restrict__ whr_ws, const uint4* __restrict__ wfr_ws,
    const float* __restrict__ invms, const float* __restrict__ inv_istr,
    const __half* __restrict__ gh_all, const __half* __restrict__ al_all,
    float* __restrict__ d_out) {
    __shared__ __align__(16) __half hdp[BPB][136];     // decayed h (A source)
    __shared__ uint4 whr_l[16 * 64];                   // 16 KB W_hr frags
    __shared__ uint4 wfr_l[8 * 64];                    // 8 KB W_fr frags
    __shared__ float  xT[2][2][64][16];                // staged x, [f][b]
    __shared__ __align__(8) __half mT[2][2][64][16];   // staged m, [f][b]
    __shared__ __align__(16) __half alA[2][2][BPB][72];// staged alpha [b][f]
    __shared__ __align__(16) __half mpA[2][2][BPB][72];// staged m f16 [b][f]
    __shared__ __align__(16) __half gams[2][2][BPB][136];
    __shared__ __align__(16) __half xcpA[4][BPB][72];  // wave-private x_c
    __shared__ __align__(16) __half ccpA[BPB][72];     // shared c_c (A source)
    __shared__ float ccst[2][BPB][68];                 // c_c f32 for imp
    __shared__ float hfin[BPB][128];
    __shared__ float sinvA[2][2];
    __shared__ float ylarr[BPB];

    const int tid = threadIdx.x;
    const int w = tid >> 6, l = tid & 63, lr = l & 15, lg = l >> 4;
    const int b0 = blockIdx.x * BPB;
    const int nb = w * 16 + lr;          // this wave's gate-slice column

    // ---- loop-invariant register weights (uniform role across waves) ----
    uint4 whhB[16];     // h-half of gates: [g][q]
    uint4 wsh[16];      // [0..7]=wic (c_c half), [8..15]=wim (m half)
    float bg4[4];
    #pragma unroll
    for (int g = 0; g < 4; g++) {
        int n = g * 128 + nb;
        #pragma unroll
        for (int q = 0; q < 4; q++) whhB[g * 4 + q] = whh_ws[(q * 4 + lg) * 512 + n];
        #pragma unroll
        for (int q = 0; q < 2; q++) {
            wsh[g * 2 + q] = wih_ws[(q * 4 + lg) * 512 + n];
            wsh[8 + g * 2 + q] = wih_ws[((q + 2) * 4 + lg) * 512 + n];
        }
        bg4[g] = b_ih[n] + b_hh[n];
    }
    float bhr4[4];
    #pragma unroll
    for (int tt = 0; tt < 4; tt++) bhr4[tt] = b_hr[tt * 16 + lr];
    const float bfr_r = b_fr[(w & 3) * 16 + lr];

    for (int o = tid; o < 1024; o += 512) whr_l[o] = whr_ws[o];
    if (tid < 512) wfr_l[tid] = wfr_ws[tid];
    for (int o = tid; o < BPB * 136; o += 512) ((__half*)hdp)[o] = __float2half(0.f);

    // ---- staging (waves 4-7) ----
    const int si = (w >= 4) ? (tid - 256) : 0;
    const int sb = si >> 4, sf = (si & 15) * 4, sc8 = (si & 15) * 8;
    const float* vpb = values + (size_t)(b0 + sb) * NT * NF;
    const float* mpb = masks + (size_t)(b0 + sb) * NT * NF;
    const __half* apb = al_all + (size_t)(b0 + sb) * NT * NF;
    const __half* gpb = gh_all + (size_t)(b0 + sb) * NT * NH;

    float4 xr[2], mr[2];
    uint2 ar[2];
    uint4 gr[2];
    float ivr[2] = {0.f, 0.f};

    if (w >= 4) {
        #pragma unroll
        for (int jj = 0; jj < 2; jj++) {
            float4 xv = *(const float4*)(vpb + (size_t)jj * NF + sf);
            float4 mv = *(const float4*)(mpb + (size_t)jj * NF + sf);
            uint2 av = *(const uint2*)(apb + (size_t)jj * NF + sf);
            uint4 gv = *(const uint4*)(gpb + (size_t)(jj + 1) * NH + sc8);
            xT[0][jj][sf + 0][sb] = xv.x; xT[0][jj][sf + 1][sb] = xv.y;
            xT[0][jj][sf + 2][sb] = xv.z; xT[0][jj][sf + 3][sb] = xv.w;
            mT[0][jj][sf + 0][sb] = __float2half(mv.x);
            mT[0][jj][sf + 1][sb] = __float2half(mv.y);
            mT[0][jj][sf + 2][sb] = __float2half(mv.z);
            mT[0][jj][sf + 3][sb] = __float2half(mv.w);
            *(uint2*)&alA[0][jj][sb][sf] = av;
            *(uint2*)&mpA[0][jj][sb][sf] = make_uint2(pack2(mv.x, mv.y), pack2(mv.z, mv.w));
            *(uint4*)&gams[0][jj][sb][sc8] = gv;
            xr[jj] = *(const float4*)(vpb + (size_t)(2 + jj) * NF + sf);
            mr[jj] = *(const float4*)(mpb + (size_t)(2 + jj) * NF + sf);
            ar[jj] = *(const uint2*)(apb + (size_t)(2 + jj) * NF + sf);
            gr[jj] = *(const uint4*)(gpb + (size_t)(3 + jj) * NH + sc8);
        }
        if (si == 0) {
            sinvA[0][0] = invms[0]; sinvA[0][1] = invms[1];
            ivr[0] = invms[2]; ivr[1] = invms[3];
        }
    }
    __syncthreads();

    float c4[4] = {0.f, 0.f, 0.f, 0.f};
    float lloss = 0.f;
    float* imp = d_out + 257;

    for (int t = 0; t < NT; ++t) {
        const int j = t & 1, buf = (t >> 1) & 1;
        f32x4 accg[4] = {{0.f,0.f,0.f,0.f},{0.f,0.f,0.f,0.f},
                         {0.f,0.f,0.f,0.f},{0.f,0.f,0.f,0.f}};

        // ===== PHASE 1 =====
        f16x8 ha[4];
        #pragma unroll
        for (int q = 0; q < 4; q++) ha[q] = ldA(&hdp[lr][0], lg, q);
        #pragma unroll
        for (int q = 0; q < 4; q++)
            #pragma unroll
            for (int g = 0; g < 4; g++)
                accg[g] = __builtin_amdgcn_mfma_f32_16x16x32_f16(ha[q], as_h8(whhB[g * 4 + q]), accg[g], 0, 0, 0);
        {
            f16x8 ma0 = ldA(&mpA[buf][j][lr][0], lg, 0);
            f16x8 ma1 = ldA(&mpA[buf][j][lr][0], lg, 1);
            #pragma unroll
            for (int g = 0; g < 4; g++) {
                accg[g] = __builtin_amdgcn_mfma_f32_16x16x32_f16(ma0, as_h8(wsh[8 + g * 2]), accg[g], 0, 0, 0);
                accg[g] = __builtin_amdgcn_mfma_f32_16x16x32_f16(ma1, as_h8(wsh[8 + g * 2 + 1]), accg[g], 0, 0, 0);
            }
        }
        if (w < 4) {
            // x_h for ALL f (redundant per wave) -> full x_c wave-locally
            f32x4 accx[4] = {{0.f,0.f,0.f,0.f},{0.f,0.f,0.f,0.f},
                             {0.f,0.f,0.f,0.f},{0.f,0.f,0.f,0.f}};
            #pragma unroll
            for (int tt = 0; tt < 4; tt++)
                #pragma unroll
                for (int q = 0; q < 4; q++)
                    accx[tt] = __builtin_amdgcn_mfma_f32_16x16x32_f16(
                        ha[q], as_h8(whr_l[(q * 4 + lg) * 64 + tt * 16 + lr]), accx[tt], 0, 0, 0);
            float xhw[4], xvw[4], mvw[4];
            #pragma unroll
            for (int tt = 0; tt < 4; tt++) {
                int f = tt * 16 + lr;
                float4 xv4 = *(const float4*)&xT[buf][j][f][lg * 4];
                uint2 mu = *(const uint2*)&mT[buf][j][f][lg * 4];
                float2 m01 = __half22float2(__builtin_bit_cast(__half2, mu.x));
                float2 m23 = __half22float2(__builtin_bit_cast(__half2, mu.y));
                #pragma unroll
                for (int e = 0; e < 4; e++) {
                    float xv = (e == 0) ? xv4.x : (e == 1) ? xv4.y : (e == 2) ? xv4.z : xv4.w;
                    float mv = (e == 0) ? m01.x : (e == 1) ? m01.y : (e == 2) ? m23.x : m23.y;
                    float xh = accx[tt][e] + bhr4[tt];
                    float xc = mv * xv + (1.f - mv) * xh;
                    xcpA[w][lg * 4 + e][f] = __float2half(xc);
                    if (tt == w) { xhw[e] = xh; xvw[e] = xv; mvw[e] = mv; }
                }
            }
            // wave-private transpose handoff: in-order DS + explicit wait
            asm volatile("s_waitcnt lgkmcnt(0)" ::: "memory");
            __builtin_amdgcn_sched_barrier(0);
            f32x4 accz = {0.f, 0.f, 0.f, 0.f};
            #pragma unroll
            for (int q = 0; q < 2; q++)
                accz = __builtin_amdgcn_mfma_f32_16x16x32_f16(
                    ldA(&xcpA[w][lr][0], lg, q), as_h8(wfr_l[(q * 4 + lg) * 64 + nb]), accz, 0, 0, 0);
            float sv = sinvA[buf][j];
            #pragma unroll
            for (int e = 0; e < 4; e++) {
                int r = lg * 4 + e;
                float av = __half2float(alA[buf][j][r][nb]);
                float zh = accz[e] + bfr_r;
                float ch = av * zh + (1.f - av) * xhw[e];
                float cc = mvw[e] * xvw[e] + (1.f - mvw[e]) * ch;
                lloss += (fabsf(xvw[e] - xhw[e]) + fabsf(xvw[e] - zh) +
                          fabsf(xvw[e] - ch)) * mvw[e] * sv;
                ccst[j][r][nb] = cc;
                ccpA[r][nb] = __float2half(cc);
            }
        } else if (j == 1) {
            // commit staged regs for steps t+1,t+2 into buf^1; issue t+3,t+4
            const int bufn = buf ^ 1;
            #pragma unroll
            for (int jj = 0; jj < 2; jj++) {
                float4 xv = xr[jj];
                float4 mv = mr[jj];
                xT[bufn][jj][sf + 0][sb] = xv.x; xT[bufn][jj][sf + 1][sb] = xv.y;
                xT[bufn][jj][sf + 2][sb] = xv.z; xT[bufn][jj][sf + 3][sb] = xv.w;
                mT[bufn][jj][sf + 0][sb] = __float2half(mv.x);
                mT[bufn][jj][sf + 1][sb] = __float2half(mv.y);
                mT[bufn][jj][sf + 2][sb] = __float2half(mv.z);
                mT[bufn][jj][sf + 3][sb] = __float2half(mv.w);
                *(uint2*)&alA[bufn][jj][sb][sf] = ar[jj];
                *(uint2*)&mpA[bufn][jj][sb][sf] = make_uint2(pack2(mv.x, mv.y), pack2(mv.z, mv.w));
                *(uint4*)&gams[bufn][jj][sb][sc8] = gr[jj];
            }
            if (si == 0) { sinvA[bufn][0] = ivr[0]; sinvA[bufn][1] = ivr[1]; }
            #pragma unroll
            for (int jj = 0; jj < 2; jj++) {
                int s = t + 3 + jj; if (s > NT - 1) s = NT - 1;
                int sg = s + 1; if (sg > NT - 1) sg = NT - 1;
                xr[jj] = *(const float4*)(vpb + (size_t)s * NF + sf);
                mr[jj] = *(const float4*)(mpb + (size_t)s * NF + sf);
                ar[jj] = *(const uint2*)(apb + (size_t)s * NF + sf);
                gr[jj] = *(const uint4*)(gpb + (size_t)sg * NH + sc8);
            }
            if (si == 0) {
                int s0 = t + 3; if (s0 > NT - 1) s0 = NT - 1;
                int s1 = t + 4; if (s1 > NT - 1) s1 = NT - 1;
                ivr[0] = invms[s0]; ivr[1] = invms[s1];
            }
        }
        bar_lds();                                     // ---- Bar C

        // ===== PHASE 2: cc-gates + pointwise =====
        {
            f16x8 ca0 = ldA(&ccpA[lr][0], lg, 0);
            f16x8 ca1 = ldA(&ccpA[lr][0], lg, 1);
            #pragma unroll
            for (int g = 0; g < 4; g++) {
                accg[g] = __builtin_amdgcn_mfma_f32_16x16x32_f16(ca0, as_h8(wsh[g * 2]), accg[g], 0, 0, 0);
                accg[g] = __builtin_amdgcn_mfma_f32_16x16x32_f16(ca1, as_h8(wsh[g * 2 + 1]), accg[g], 0, 0, 0);
            }
        }
        #pragma unroll
        for (int e = 0; e < 4; e++) {
            int r = lg * 4 + e;
            float gi = accg[0][e] + bg4[0];
            float gf = accg[1][e] + bg4[1];
            float gg = accg[2][e] + bg4[2];
            float go = accg[3][e] + bg4[3];
            float cn = sigm(gf) * c4[e] + sigm(gi) * tanh_fast(gg);
            c4[e] = cn;
            float hn = sigm(go) * tanh_fast(cn);
            float gm = __half2float(gams[buf][j][r][nb]);
            hdp[r][nb] = __float2half(hn * gm);
            if (t == NT - 1) hfin[r][nb] = hn;
        }
        if (w >= 4 && j == 1) {
            // coalesced imp stores for steps t-1 and t
            #pragma unroll
            for (int jj = 0; jj < 2; jj++) {
                int ts = t - 1 + jj;
                #pragma unroll
                for (int k = 0; k < 4; k++) {
                    int idx = si + k * 256;
                    int ff = idx & 63, bb = idx >> 6;
                    imp[((size_t)(b0 + bb) * NT + ts) * NF + ff] = ccst[jj][bb][ff];
                }
            }
        }
        bar_lds();                                     // ---- Bar T
    }

    __syncthreads();
    // ---- finale: loss reduce, y_h per batch, BCE, atomic ----
    float* redl = &ccst[0][0][0];
    redl[tid] = lloss;
    __syncthreads();
    for (int off = 256; off > 0; off >>= 1) {
        if (tid < off) redl[tid] += redl[tid + off];
        __syncthreads();
    }
    if (tid < BPB) {
        float yp = 0.f;
        for (int c = 0; c < 128; c++) yp += hfin[tid][c] * W_out[c];
        float yh = yp + b_out[0];
        d_out[1 + b0 + tid] = 1.f / (1.f + expf(-yh));
        float lab = labels[b0 + tid], istr = is_train[b0 + tid];
        float maxv = fmaxf(-yh, 0.f);
        float yl = yh - yh * lab + maxv + logf(expf(-maxv) + expf(-yh - maxv));
        ylarr[tid] = yl * istr;
    }
    __syncthreads();
    if (tid == 0) {
        float s = 0.f;
        for (int i = 0; i < BPB; i++) s += ylarr[i];
        atomicAdd(d_out, redl[0] * (1.f / (float)NT) + 0.3f * s * (*inv_istr));
    }
}

// ---------------------------------------------------------------------------
extern "C" void kernel_launch(void* const* d_in, const int* in_sizes, int n_in,
                              void* d_out, int out_size, void* d_ws, size_t ws_size,
                              hipStream_t stream) {
    const float* values = (const float*)d_in[0];
    const float* masks = (const float*)d_in[1];
    const float* deltas = (const float*)d_in[2];
    const float* labels = (const float*)d_in[3];
    const float* is_train = (const float*)d_in[4];
    const float* W_dh = (const float*)d_in[5];
    const float* b_dh = (const float*)d_in[6];
    const float* W_dx = (const float*)d_in[7];
    const float* b_dx = (const float*)d_in[8];
    const float* W_hr = (const float*)d_in[9];
    const float* b_hr = (const float*)d_in[10];
    const float* W_fr = (const float*)d_in[11];
    const float* b_fr = (const float*)d_in[12];
    const float* W_wc = (const float*)d_in[13];
    const float* b_wc = (const float*)d_in[14];
    const float* W_ih = (const float*)d_in[15];
    const float* b_ih = (const float*)d_in[16];
    const float* W_hh = (const float*)d_in[17];
    const float* b_hh = (const float*)d_in[18];
    const float* W_out = (const float*)d_in[19];
    const float* b_out = (const float*)d_in[20];

    char* ws = (char*)d_ws;
    unsigned* wsu = (unsigned*)d_ws;
    const uint4* whh_ws = (const uint4*)(ws + WHH_OFF);
    const uint4* wih_ws = (const uint4*)(ws + WIH_OFF);
    const uint4* whr_ws = (const uint4*)(ws + WHR_OFF);
    const uint4* wfr_ws = (const uint4*)(ws + WFR_OFF);
    float* invms = (float*)(ws + INVMS_OFF);
    float* inv_istr = (float*)(ws + ISTR_OFF);
    __half* gh_all = (__half*)(ws + GH_OFF);
    __half* al_all = (__half*)(ws + AL_OFF);
    float* out_f = (float*)d_out;

    prep_w<<<280, 256, 0, stream>>>(W_hh, W_ih, W_hr, W_fr, wsu);
    prep_msum<<<513, 256, 0, stream>>>(masks, is_train, invms, inv_istr, out_f);
    ga_kernel<<<4096, 256, 0, stream>>>(deltas, masks, W_dh, b_dh, W_dx, b_dx,
                                        W_wc, b_wc, gh_all, al_all);
    main_kernel<<<NBATCH / BPB, 512, 0, stream>>>(values, masks, labels, is_train,
                                                  b_hr, b_fr, b_ih, b_hh, W_out, b_out,
                                                  whh_ws, wih_ws, whr_ws, wfr_ws,
                                                  invms, inv_istr, gh_all, al_all,
                                                  out_f);
}